// Round 5
// baseline (346.512 us; speedup 1.0000x reference)
//
#include <hip/hip_runtime.h>
#include <hip/hip_fp16.h>
#include <stdint.h>

typedef _Float16 half_t;
typedef __attribute__((ext_vector_type(8))) _Float16 half8;   // MFMA A/B frag (4 VGPRs)
typedef __attribute__((ext_vector_type(16))) float f32x16;    // 32x32 MFMA C/D frag
typedef __attribute__((ext_vector_type(4)))  float float4v;

#define BM 128
#define BN 128
#define BK 64   // 8 chunks of 8 halves (16 B) per row

// Raw workgroup barrier that waits ONLY on LDS ops — in-flight global loads
// (which target private VGPRs, not LDS) legally stay outstanding across it.
// This is the whole point of the reg-staged pipeline: __syncthreads() would
// force s_waitcnt vmcnt(0) and drain the prefetch.
#define BAR_LGKM() asm volatile("s_waitcnt lgkmcnt(0)\n\ts_barrier" ::: "memory")

// ---------------------------------------------------------------------------
// Merged fp32->fp16 RNE quantize for BOTH tensors in one dispatch.
// == reference _quantize (e5m10, RNE, HW denormals). 8 elems/thread.
// (R1-R4: residue is insensitive to quant structure; frozen.)
// ---------------------------------------------------------------------------
__global__ void quant_both(const float* __restrict__ inA,
                           const float* __restrict__ inB,
                           half_t* __restrict__ out, long na, long ntot) {
    long i = ((long)blockIdx.x * blockDim.x + threadIdx.x) * 8;
    if (i + 8 > ntot) {
        for (; i < ntot; ++i)
            out[i] = (half_t)(i < na ? inA[i] : inB[i - na]);
        return;
    }
    const float* src = (i < na) ? (inA + i) : (inB + (i - na));
    float4v v0 = *(const float4v*)(src);
    float4v v1 = *(const float4v*)(src + 4);
    half8 h;
    h[0] = (half_t)v0[0]; h[1] = (half_t)v0[1];
    h[2] = (half_t)v0[2]; h[3] = (half_t)v0[3];
    h[4] = (half_t)v1[0]; h[5] = (half_t)v1[1];
    h[6] = (half_t)v1[2]; h[7] = (half_t)v1[3];
    *(half8*)(out + i) = h;
}

// ---------------------------------------------------------------------------
// Register-staged double-buffered GEMM.
// C[m][n] = sum_k A[m][k]*B[n][k] + q(bias[n]).  Both operands K-contiguous.
// 128x128 tile, BK=64, 4 waves (2x2 of 64x64), mfma_f32_32x32x16_f16,
// XOR chunk swizzle on LDS k-chunks (chunk (row,pos) holds k-chunk
// pos^(row&7)).
// K-loop per tile:
//   1. issue next tile's 8x global_load_dwordx4 into VGPRs (no LDS target)
//   2. 16 MFMAs from current LDS tile
//   3. lgkm-only barrier (LDS reads done; global loads REMAIN IN FLIGHT)
//   4. ds_write_b128 regs->LDS (compiler waits vmcnt per-reg here, after a
//      full compute phase of latency hiding)
//   5. lgkm-only barrier (writes visible)
// Neither barrier drains vmcnt — removes the m97-structure ~20% stall.
// ---------------------------------------------------------------------------
__global__ __launch_bounds__(256)
void gemm_qf16_dbuf(const half_t* __restrict__ A, const half_t* __restrict__ B,
                    const float* __restrict__ bias, float* __restrict__ C,
                    int M, int N, int K) {
    __shared__ half_t sA[BM * BK];   // 16 KB
    __shared__ half_t sB[BN * BK];   // 16 KB

    const int t    = threadIdx.x;
    const int lane = t & 63;
    const int wave = t >> 6;
    const int wm   = (wave >> 1) * 64;
    const int wn   = (wave & 1) * 64;

    // XCD-aware block swizzle (kept from R4; free)
    const int nbx = N / BN, nby = M / BM;
    int bxi, byi;
    {
        const int b = blockIdx.x;
        if (nbx == 32 && nby == 32) {
            const int xcd = b & 7;
            const int s   = b >> 3;
            bxi = xcd * 4 + (s & 3);
            byi = s >> 2;
        } else {
            bxi = b % nbx;
            byi = b / nbx;
        }
    }
    const int bm = byi * BM;
    const int bn = bxi * BN;

    // staging: 1024 16B-chunks per matrix, 4 per thread; chunk c = t + 256*s:
    // row = c>>3, LDS pos = c&7, global k-chunk = (c&7) ^ (row&7)
    long offA[4], offB[4];
    #pragma unroll
    for (int s = 0; s < 4; ++s) {
        const int c   = t + 256 * s;
        const int row = c >> 3;
        const int kc  = (c & 7) ^ (row & 7);
        offA[s] = (long)(bm + row) * K + kc * 8;
        offB[s] = (long)(bn + row) * K + kc * 8;
    }

    f32x16 acc[2][2] = {};

    const int ml = lane & 31;   // m (or n) within 32-tile
    const int kg = lane >> 5;   // which 8-k half of the MFMA's K=16
    const int sw = ml & 7;      // row component of the XOR swizzle

    half8 pa[4], pb[4];

    // prologue: tile 0 through regs into LDS
    #pragma unroll
    for (int s = 0; s < 4; ++s) {
        pa[s] = *(const half8*)(A + offA[s]);
        pb[s] = *(const half8*)(B + offB[s]);
    }
    #pragma unroll
    for (int s = 0; s < 4; ++s) {
        *(half8*)&sA[(t + 256 * s) * 8] = pa[s];
        *(half8*)&sB[(t + 256 * s) * 8] = pb[s];
    }
    BAR_LGKM();

    for (int k0 = 0; k0 < K; k0 += BK) {
        const bool more = (k0 + BK) < K;
        if (more) {
            // 1. issue next tile's loads into regs (stay in flight past bar)
            #pragma unroll
            for (int s = 0; s < 4; ++s) {
                pa[s] = *(const half8*)(A + offA[s] + k0 + BK);
                pb[s] = *(const half8*)(B + offB[s] + k0 + BK);
            }
        }
        // 2. compute current tile from LDS
        #pragma unroll
        for (int ks = 0; ks < 4; ++ks) {
            const int cp = 2 * ks + kg;                    // k-chunk 0..7
            half8 a0 = *(const half8*)&sA[((wm      + ml) * 8 + (cp ^ sw)) * 8];
            half8 a1 = *(const half8*)&sA[((wm + 32 + ml) * 8 + (cp ^ sw)) * 8];
            half8 b0 = *(const half8*)&sB[((wn      + ml) * 8 + (cp ^ sw)) * 8];
            half8 b1 = *(const half8*)&sB[((wn + 32 + ml) * 8 + (cp ^ sw)) * 8];
            acc[0][0] = __builtin_amdgcn_mfma_f32_32x32x16_f16(a0, b0, acc[0][0], 0, 0, 0);
            acc[0][1] = __builtin_amdgcn_mfma_f32_32x32x16_f16(a0, b1, acc[0][1], 0, 0, 0);
            acc[1][0] = __builtin_amdgcn_mfma_f32_32x32x16_f16(a1, b0, acc[1][0], 0, 0, 0);
            acc[1][1] = __builtin_amdgcn_mfma_f32_32x32x16_f16(a1, b1, acc[1][1], 0, 0, 0);
        }
        if (more) {
            // 3. LDS reads done (loads still in flight)
            BAR_LGKM();
            // 4. commit prefetched tile (vmcnt waits happen here, per-reg)
            #pragma unroll
            for (int s = 0; s < 4; ++s) {
                *(half8*)&sA[(t + 256 * s) * 8] = pa[s];
                *(half8*)&sB[(t + 256 * s) * 8] = pb[s];
            }
            // 5. writes visible
            BAR_LGKM();
        }
    }

    // Epilogue. 32x32 C/D layout [m74/m101]: col = lane&31,
    // row = (reg&3) + 8*(reg>>2) + 4*(lane>>5)
    const int cl = lane & 31;
    const int rb = 4 * (lane >> 5);
    #pragma unroll
    for (int j = 0; j < 2; ++j) {
        const int col = bn + wn + j * 32 + cl;
        const float bq = (float)(half_t)bias[col];   // inline bias quantize
        #pragma unroll
        for (int i = 0; i < 2; ++i) {
            #pragma unroll
            for (int r = 0; r < 16; ++r) {
                const int row = bm + wm + i * 32 + (r & 3) + 8 * (r >> 2) + rb;
                C[(long)row * N + col] = acc[i][j][r] + bq;
            }
        }
    }
}

// ---------------------------------------------------------------------------
// Fallback: fused fp32->fp16 conversion during staging (used only if d_ws is
// too small). Classic __syncthreads structure — correctness path.
// ---------------------------------------------------------------------------
__global__ __launch_bounds__(256)
void gemm_qf16_fused(const float* __restrict__ A, const float* __restrict__ B,
                     const float* __restrict__ bias, float* __restrict__ C,
                     int M, int N, int K) {
    __shared__ half_t sA[BM * BK];
    __shared__ half_t sB[BN * BK];

    const int t    = threadIdx.x;
    const int lane = t & 63;
    const int wave = t >> 6;
    const int wm   = (wave >> 1) * 64;
    const int wn   = (wave & 1) * 64;
    const int bm   = (blockIdx.x / (N / BN)) * BM;
    const int bn   = (blockIdx.x % (N / BN)) * BN;

    int srow[4], skc[4];
    #pragma unroll
    for (int s = 0; s < 4; ++s) {
        const int c = t + 256 * s;
        srow[s] = c >> 3;
        skc[s]  = (c & 7) ^ (srow[s] & 7);
    }

    f32x16 acc[2][2] = {};
    const int ml = lane & 31;
    const int kg = lane >> 5;
    const int sw = ml & 7;

    for (int k0 = 0; k0 < K; k0 += BK) {
        #pragma unroll
        for (int s = 0; s < 4; ++s) {
            const long ga = (long)(bm + srow[s]) * K + k0 + skc[s] * 8;
            const long gb = (long)(bn + srow[s]) * K + k0 + skc[s] * 8;
            float4v a0 = *(const float4v*)(A + ga);
            float4v a1 = *(const float4v*)(A + ga + 4);
            float4v b0 = *(const float4v*)(B + gb);
            float4v b1 = *(const float4v*)(B + gb + 4);
            half8 ha, hb;
            ha[0]=(half_t)a0[0]; ha[1]=(half_t)a0[1]; ha[2]=(half_t)a0[2]; ha[3]=(half_t)a0[3];
            ha[4]=(half_t)a1[0]; ha[5]=(half_t)a1[1]; ha[6]=(half_t)a1[2]; ha[7]=(half_t)a1[3];
            hb[0]=(half_t)b0[0]; hb[1]=(half_t)b0[1]; hb[2]=(half_t)b0[2]; hb[3]=(half_t)b0[3];
            hb[4]=(half_t)b1[0]; hb[5]=(half_t)b1[1]; hb[6]=(half_t)b1[2]; hb[7]=(half_t)b1[3];
            *(half8*)&sA[(t + 256 * s) * 8] = ha;
            *(half8*)&sB[(t + 256 * s) * 8] = hb;
        }
        __syncthreads();

        #pragma unroll
        for (int ks = 0; ks < 4; ++ks) {
            const int cp = 2 * ks + kg;
            half8 a0 = *(const half8*)&sA[((wm      + ml) * 8 + (cp ^ sw)) * 8];
            half8 a1 = *(const half8*)&sA[((wm + 32 + ml) * 8 + (cp ^ sw)) * 8];
            half8 b0 = *(const half8*)&sB[((wn      + ml) * 8 + (cp ^ sw)) * 8];
            half8 b1 = *(const half8*)&sB[((wn + 32 + ml) * 8 + (cp ^ sw)) * 8];
            acc[0][0] = __builtin_amdgcn_mfma_f32_32x32x16_f16(a0, b0, acc[0][0], 0, 0, 0);
            acc[0][1] = __builtin_amdgcn_mfma_f32_32x32x16_f16(a0, b1, acc[0][1], 0, 0, 0);
            acc[1][0] = __builtin_amdgcn_mfma_f32_32x32x16_f16(a1, b0, acc[1][0], 0, 0, 0);
            acc[1][1] = __builtin_amdgcn_mfma_f32_32x32x16_f16(a1, b1, acc[1][1], 0, 0, 0);
        }
        __syncthreads();
    }

    const int cl = lane & 31;
    const int rb = 4 * (lane >> 5);
    #pragma unroll
    for (int j = 0; j < 2; ++j) {
        const int col = bn + wn + j * 32 + cl;
        const float bq = (float)(half_t)bias[col];
        #pragma unroll
        for (int i = 0; i < 2; ++i) {
            #pragma unroll
            for (int r = 0; r < 16; ++r) {
                const int row = bm + wm + i * 32 + (r & 3) + 8 * (r >> 2) + rb;
                C[(long)row * N + col] = acc[i][j][r] + bq;
            }
        }
    }
}

extern "C" void kernel_launch(void* const* d_in, const int* in_sizes, int n_in,
                              void* d_out, int out_size, void* d_ws, size_t ws_size,
                              hipStream_t stream) {
    const float* x    = (const float*)d_in[0];
    const float* w    = (const float*)d_in[1];
    const float* bias = (const float*)d_in[2];
    float* out = (float*)d_out;

    const int OUT = in_sizes[2];
    const int IN  = in_sizes[1] / OUT;
    const int M   = in_sizes[0] / IN;
    const int N   = OUT, K = IN;

    dim3 grid((N / BN) * (M / BM));
    const size_t needed = ((size_t)M * K + (size_t)N * K) * sizeof(half_t);

    if (ws_size >= needed) {
        half_t* q = (half_t*)d_ws;          // qa at 0, qb at M*K (contiguous)
        const long na = (long)M * K, ntot = na + (long)N * K;
        const long per = 8L * 256;
        quant_both<<<(int)((ntot + per - 1) / per), 256, 0, stream>>>(x, w, q, na, ntot);
        gemm_qf16_dbuf<<<grid, 256, 0, stream>>>(q, q + na, bias, out, M, N, K);
    } else {
        gemm_qf16_fused<<<grid, 256, 0, stream>>>(x, w, bias, out, M, N, K);
    }
}